// Round 2
// baseline (200.469 us; speedup 1.0000x reference)
//
#include <hip/hip_runtime.h>
#include <hip/hip_bf16.h>

#define TDEPTH 6
#define NLEAF 64
#define NGATE 63
#define INF 512
#define OUTF 512
#define BATCH 1024

#define BM 128
#define BN 64
#define SPLITK 8
#define KCH 513   // 512 real i-chunks + 1 virtual chunk (x==1) for the pb bias term

typedef __attribute__((ext_vector_type(4))) float f32x4;
typedef __attribute__((ext_vector_type(8))) __bf16 bf16x8;

// ---------------- kernel 1: leaf probabilities ----------------
__global__ __launch_bounds__(256) void leaf_kernel(
    const float* __restrict__ x, const float* __restrict__ gw,
    const float* __restrict__ gb, float* __restrict__ leaf) {
  const int wid = threadIdx.x >> 6, lane = threadIdx.x & 63;
  const int b = blockIdx.x * 4 + wid;
  __shared__ float g[4][NLEAF];
  if (lane < NGATE) {
    const float* xr = x + (size_t)b * INF;
    float a0 = 0.f, a1 = 0.f, a2 = 0.f, a3 = 0.f;
    #pragma unroll 4
    for (int i = 0; i < INF; i += 4) {
      a0 += xr[i + 0] * gw[(i + 0) * NGATE + lane];
      a1 += xr[i + 1] * gw[(i + 1) * NGATE + lane];
      a2 += xr[i + 2] * gw[(i + 2) * NGATE + lane];
      a3 += xr[i + 3] * gw[(i + 3) * NGATE + lane];
    }
    float t = (a0 + a1) + (a2 + a3) + gb[lane];
    g[wid][lane] = 1.0f / (1.0f + __expf(-t));
  }
  __syncthreads();
  float p = 1.0f;
  #pragma unroll
  for (int d = 0; d < TDEPTH; d++) {
    int prefix = lane >> (TDEPTH - 1 - d);
    int node = (1 << d) - 1 + (prefix >> 1);
    float gv = g[wid][node];
    p *= (prefix & 1) ? (1.0f - gv) : gv;
  }
  leaf[(size_t)b * NLEAF + lane] = p;
}

// ---------------- kernel 2: barrier-free fused GEMM ----------------
// partial[s][b][o] = sum over K-slice of (x[b,i]*leaf[b,l]) * pw[o,i,l]
// All fragments built in registers; no LDS, no __syncthreads in the K-loop.
__device__ __forceinline__ void load_step(
    int i, const float* const (&pB)[2], const float* const (&pPB)[2],
    const float* const (&pX)[4], int l0,
    f32x4 (&B)[2][2][2], float (&xv)[4]) {
  if (i < INF) {
    #pragma unroll
    for (int ni = 0; ni < 2; ni++) {
      const float* src = pB[ni] + (size_t)i * NLEAF + l0;
      #pragma unroll
      for (int kk = 0; kk < 2; kk++)
        #pragma unroll
        for (int h = 0; h < 2; h++)
          B[ni][kk][h] = *(const f32x4*)(src + kk * 32 + h * 4);
    }
    #pragma unroll
    for (int mi = 0; mi < 4; mi++) xv[mi] = pX[mi][i];
  } else {  // virtual bias chunk: x==1, weights = pb
    #pragma unroll
    for (int ni = 0; ni < 2; ni++) {
      const float* src = pPB[ni] + l0;
      #pragma unroll
      for (int kk = 0; kk < 2; kk++)
        #pragma unroll
        for (int h = 0; h < 2; h++)
          B[ni][kk][h] = *(const f32x4*)(src + kk * 32 + h * 4);
    }
    #pragma unroll
    for (int mi = 0; mi < 4; mi++) xv[mi] = 1.0f;
  }
}

__device__ __forceinline__ void compute_step(
    const f32x4 (&B)[2][2][2], const float (&xv)[4],
    const f32x4 (&lf)[4][2][2], f32x4 (&acc)[4][2]) {
  bf16x8 bfr[2][2];
  #pragma unroll
  for (int ni = 0; ni < 2; ni++)
    #pragma unroll
    for (int kk = 0; kk < 2; kk++) {
      f32x4 lo = B[ni][kk][0], hi = B[ni][kk][1];
      bf16x8 t;
      t[0] = (__bf16)lo[0]; t[1] = (__bf16)lo[1];
      t[2] = (__bf16)lo[2]; t[3] = (__bf16)lo[3];
      t[4] = (__bf16)hi[0]; t[5] = (__bf16)hi[1];
      t[6] = (__bf16)hi[2]; t[7] = (__bf16)hi[3];
      bfr[ni][kk] = t;
    }
  #pragma unroll
  for (int mi = 0; mi < 4; mi++) {
    #pragma unroll
    for (int kk = 0; kk < 2; kk++) {
      f32x4 p0 = lf[mi][kk][0] * xv[mi];
      f32x4 p1 = lf[mi][kk][1] * xv[mi];
      bf16x8 a;
      a[0] = (__bf16)p0[0]; a[1] = (__bf16)p0[1];
      a[2] = (__bf16)p0[2]; a[3] = (__bf16)p0[3];
      a[4] = (__bf16)p1[0]; a[5] = (__bf16)p1[1];
      a[6] = (__bf16)p1[2]; a[7] = (__bf16)p1[3];
      #pragma unroll
      for (int ni = 0; ni < 2; ni++)
        acc[mi][ni] = __builtin_amdgcn_mfma_f32_16x16x32_bf16(
            a, bfr[ni][kk], acc[mi][ni], 0, 0, 0);
    }
  }
}

__global__ __launch_bounds__(256, 2) void gemm_kernel(
    const float* __restrict__ x, const float* __restrict__ pw,
    const float* __restrict__ pb, const float* __restrict__ leaf,
    float* __restrict__ partial) {
  const int tid = threadIdx.x;
  const int lane = tid & 63;
  const int wid = tid >> 6;
  // XCD swizzle: the 8 mb-blocks sharing a (nb,s) B-slice land on one XCD
  const int L = (blockIdx.x & 7) * 64 + (blockIdx.x >> 3);
  const int mb = L & 7, nb = (L >> 3) & 7, s = L >> 6;
  const int m0 = mb * BM, n0 = nb * BN;
  const int cs = (s * KCH) / SPLITK;
  const int ce = ((s + 1) * KCH) / SPLITK;

  const int wm = wid >> 1, wn = wid & 1;  // wave tile: 64 rows x 32 cols
  const int q = lane >> 4, rl = lane & 15;
  const int l0 = q * 8;

  // persistent pointers (per-lane)
  const float* pB[2];   // pw rows for this lane's two o-columns
  const float* pPB[2];  // pb rows (bias chunk)
  const float* pX[4];   // x rows for this lane's four m-rows
  #pragma unroll
  for (int ni = 0; ni < 2; ni++) {
    int o = n0 + wn * 32 + ni * 16 + rl;
    pB[ni]  = pw + (size_t)o * (INF * NLEAF);
    pPB[ni] = pb + (size_t)o * NLEAF;
  }
  #pragma unroll
  for (int mi = 0; mi < 4; mi++)
    pX[mi] = x + (size_t)(m0 + wm * 64 + mi * 16 + rl) * INF;

  // leaf fragments: resident in VGPRs for the whole K-loop (64 f32)
  f32x4 lf[4][2][2];
  #pragma unroll
  for (int mi = 0; mi < 4; mi++) {
    const float* lr = leaf + (size_t)(m0 + wm * 64 + mi * 16 + rl) * NLEAF + l0;
    #pragma unroll
    for (int kk = 0; kk < 2; kk++)
      #pragma unroll
      for (int h = 0; h < 2; h++)
        lf[mi][kk][h] = *(const f32x4*)(lr + kk * 32 + h * 4);
  }

  f32x4 acc[4][2];
  #pragma unroll
  for (int mi = 0; mi < 4; mi++)
    #pragma unroll
    for (int ni = 0; ni < 2; ni++) acc[mi][ni] = (f32x4){0.f, 0.f, 0.f, 0.f};

  // register double-buffered K-loop (named buffers -> static indexing)
  const int nst = ce - cs;
  f32x4 Ba[2][2][2], Bb[2][2][2];
  float xa[4], xb[4];
  load_step(cs, pB, pPB, pX, l0, Ba, xa);
  int k = 0;
  for (; k + 2 <= nst; k += 2) {
    load_step(cs + k + 1, pB, pPB, pX, l0, Bb, xb);
    compute_step(Ba, xa, lf, acc);
    if (k + 2 < nst) load_step(cs + k + 2, pB, pPB, pX, l0, Ba, xa);
    compute_step(Bb, xb, lf, acc);
  }
  if (k < nst) compute_step(Ba, xa, lf, acc);

  // epilogue: partial[s][m0+row][n0+col]
  float* dst = partial + ((size_t)s * BATCH + m0) * OUTF + n0;
  #pragma unroll
  for (int mi = 0; mi < 4; mi++)
    #pragma unroll
    for (int ni = 0; ni < 2; ni++)
      #pragma unroll
      for (int r = 0; r < 4; r++) {
        int row = wm * 64 + mi * 16 + q * 4 + r;  // D row = (lane>>4)*4 + reg
        int col = wn * 32 + ni * 16 + rl;         // D col = lane&15
        dst[(size_t)row * OUTF + col] = acc[mi][ni][r];
      }
}

// ---------------- kernel 3: split-K reduce ----------------
__global__ __launch_bounds__(256) void reduce_kernel(
    const float* __restrict__ partial, float* __restrict__ out) {
  size_t e = ((size_t)blockIdx.x * 256 + threadIdx.x) * 4;
  f32x4 sum = (f32x4){0.f, 0.f, 0.f, 0.f};
  #pragma unroll
  for (int s = 0; s < SPLITK; s++)
    sum += *(const f32x4*)(partial + (size_t)s * BATCH * OUTF + e);
  *(f32x4*)(out + e) = sum;
}

extern "C" void kernel_launch(void* const* d_in, const int* in_sizes, int n_in,
                              void* d_out, int out_size, void* d_ws, size_t ws_size,
                              hipStream_t stream) {
  const float* x  = (const float*)d_in[0];
  const float* gw = (const float*)d_in[1];
  const float* gb = (const float*)d_in[2];
  const float* pw = (const float*)d_in[3];
  const float* pb = (const float*)d_in[4];
  float* out = (float*)d_out;

  float* leaf    = (float*)d_ws;                       // 256 KB
  float* partial = (float*)((char*)d_ws + (1 << 20));  // 16 MB

  leaf_kernel<<<BATCH / 4, 256, 0, stream>>>(x, gw, gb, leaf);
  gemm_kernel<<<(BATCH / BM) * (OUTF / BN) * SPLITK, 256, 0, stream>>>(
      x, pw, pb, leaf, partial);
  reduce_kernel<<<(BATCH * OUTF) / (256 * 4), 256, 0, stream>>>(partial, out);
}

// Round 3
// 72.617 us; speedup vs baseline: 2.7606x; 2.7606x over previous
//
#include <hip/hip_runtime.h>
#include <hip/hip_bf16.h>

#define TDEPTH 6
#define NLEAF 64
#define NGATE 63
#define INF 512
#define OUTF 512
#define BATCH 1024

#define BM 256
#define BN 128
#define SPLITK 16
#define KCH 513     // 512 real i-chunks + 1 virtual bias chunk (x==1, W=pb)
#define THREADS 512
#define XPITCH 36   // f32 pitch for x slice (16B-aligned rows, odd-ish banks)

typedef __attribute__((ext_vector_type(4))) float f32x4;
typedef __attribute__((ext_vector_type(4))) __bf16 bf16x4;
typedef __attribute__((ext_vector_type(8))) __bf16 bf16x8;

// ---------------- kernel 1: leaf probabilities ----------------
__global__ __launch_bounds__(256) void leaf_kernel(
    const float* __restrict__ x, const float* __restrict__ gw,
    const float* __restrict__ gb, float* __restrict__ leaf) {
  const int wid = threadIdx.x >> 6, lane = threadIdx.x & 63;
  const int b = blockIdx.x * 4 + wid;
  __shared__ float g[4][NLEAF];
  if (lane < NGATE) {
    const float* xr = x + (size_t)b * INF;
    float a0 = 0.f, a1 = 0.f, a2 = 0.f, a3 = 0.f;
    #pragma unroll 4
    for (int i = 0; i < INF; i += 4) {
      a0 += xr[i + 0] * gw[(i + 0) * NGATE + lane];
      a1 += xr[i + 1] * gw[(i + 1) * NGATE + lane];
      a2 += xr[i + 2] * gw[(i + 2) * NGATE + lane];
      a3 += xr[i + 3] * gw[(i + 3) * NGATE + lane];
    }
    float t = (a0 + a1) + (a2 + a3) + gb[lane];
    g[wid][lane] = 1.0f / (1.0f + __expf(-t));
  }
  __syncthreads();
  float p = 1.0f;
  #pragma unroll
  for (int d = 0; d < TDEPTH; d++) {
    int prefix = lane >> (TDEPTH - 1 - d);
    int node = (1 << d) - 1 + (prefix >> 1);
    float gv = g[wid][node];
    p *= (prefix & 1) ? (1.0f - gv) : gv;
  }
  leaf[(size_t)b * NLEAF + lane] = p;
}

// ---------------- kernel 2: hybrid fused GEMM ----------------
// A-frags in registers (lf resident, x from LDS); B staged coalesced ->
// bf16 XOR-swizzled LDS, double-buffered, one barrier per K-step.
__device__ __forceinline__ void load_b4(f32x4 (&bv)[4], const float* src) {
  #pragma unroll
  for (int j = 0; j < 4; j++) bv[j] = *(const f32x4*)(src + j * 16);
}

__device__ __forceinline__ void store_b(__bf16* Bb, int bo, int c,
                                        const f32x4 (&bv)[4]) {
  const int swz = (bo & 7) << 4;
  #pragma unroll
  for (int j = 0; j < 4; j++) {
    bf16x4 w;
    w[0] = (__bf16)bv[j][0]; w[1] = (__bf16)bv[j][1];
    w[2] = (__bf16)bv[j][2]; w[3] = (__bf16)bv[j][3];
    int byte = bo * 128 + ((c * 8 + j * 32) ^ swz);
    *(bf16x4*)((char*)Bb + byte) = w;
  }
}

__global__ __launch_bounds__(THREADS, 2) void gemm_kernel(
    const float* __restrict__ x, const float* __restrict__ pw,
    const float* __restrict__ pb, const float* __restrict__ leaf,
    float* __restrict__ partial) {
  __shared__ float xsm[BM * XPITCH];       // 36.9 KB
  __shared__ __bf16 Bsm[2][BN * 64];       // 2 x 16 KB, swizzled 128B rows

  const int tid = threadIdx.x;
  const int lane = tid & 63;
  const int wid = tid >> 6;
  const int wm = wid >> 1, wn = wid & 1;   // 4x2 wave grid, 64x64 per wave
  const int q = lane >> 4, rl = lane & 15;

  // XCD-chunked swizzle: 4 mb-blocks of one (nb,s) group land on one XCD
  const int bid = blockIdx.x;
  const int L = (bid & 7) * 32 + (bid >> 3);
  const int mb = L & 3, g = L >> 2;
  const int nb = g >> 4, s = g & 15;
  const int m0 = mb * BM, n0 = nb * BN;
  const int cs = (s * KCH) / SPLITK;
  const int ce = ((s + 1) * KCH) / SPLITK;
  const int nreal = min(ce, INF) - cs;     // 32 for all s
  const bool bias_tile = (ce == KCH);      // only s == SPLITK-1

  // leaf fragments -> registers (row = lane's A-frag row, cols q*8+kk*32..+8)
  f32x4 lf[4][2][2];
  #pragma unroll
  for (int mi = 0; mi < 4; mi++) {
    const float* lr = leaf + (size_t)(m0 + wm * 64 + mi * 16 + rl) * NLEAF + q * 8;
    #pragma unroll
    for (int kk = 0; kk < 2; kk++) {
      lf[mi][kk][0] = *(const f32x4*)(lr + kk * 32);
      lf[mi][kk][1] = *(const f32x4*)(lr + kk * 32 + 4);
    }
  }

  // stage x slice once: rows m0..m0+255, i in [cs, cs+32)
  {
    int r = tid >> 1, h = tid & 1;
    const float* src = x + (size_t)(m0 + r) * INF + cs + h * 16;
    float* dst = xsm + r * XPITCH + h * 16;
    #pragma unroll
    for (int j = 0; j < 4; j++) *(f32x4*)(dst + j * 4) = *(const f32x4*)(src + j * 4);
  }

  // B staging assignment: 4 lanes per row, per-inst coalesced 64B lines
  const int bo = tid >> 2;            // 0..127 (o within BN)
  const int bc = tid & 3;             // quarter: f32 cols bc*4 + j*16
  const float* pwrow = pw + (size_t)(n0 + bo) * (INF * NLEAF) + bc * 4;
  const float* pbrow = pb + (size_t)(n0 + bo) * NLEAF + bc * 4;

  f32x4 acc[4][4];
  #pragma unroll
  for (int mi = 0; mi < 4; mi++)
    #pragma unroll
    for (int ni = 0; ni < 4; ni++) acc[mi][ni] = (f32x4){0.f, 0.f, 0.f, 0.f};

  // prologue: stage first B tile
  f32x4 bv[4];
  load_b4(bv, pwrow + (size_t)cs * NLEAF);
  store_b(Bsm[0], bo, bc, bv);
  __syncthreads();

  #pragma unroll 2
  for (int t = 0; t < nreal; t++) {
    const int cur = t & 1, nxt = cur ^ 1;
    const bool more = (t + 1 < nreal) || bias_tile;
    const bool next_is_bias = (t + 1 >= nreal);
    if (more) {
      if (!next_is_bias) load_b4(bv, pwrow + (size_t)(cs + t + 1) * NLEAF);
      else               load_b4(bv, pbrow);
    }
    // x values for this step (broadcast across q)
    float xv[4];
    #pragma unroll
    for (int mi = 0; mi < 4; mi++)
      xv[mi] = xsm[(wm * 64 + mi * 16 + rl) * XPITCH + t];
    // MFMA: per kk, read 4 B-frags then 4x4 MFMAs with reg-built A
    #pragma unroll
    for (int kk = 0; kk < 2; kk++) {
      bf16x8 bfr[4];
      #pragma unroll
      for (int ni = 0; ni < 4; ni++) {
        int row = wn * 64 + ni * 16 + rl;
        int byte = row * 128 + ((kk * 64 + q * 16) ^ ((row & 7) << 4));
        bfr[ni] = *(const bf16x8*)((const char*)Bsm[cur] + byte);
      }
      #pragma unroll
      for (int mi = 0; mi < 4; mi++) {
        f32x4 p0 = lf[mi][kk][0] * xv[mi];
        f32x4 p1 = lf[mi][kk][1] * xv[mi];
        bf16x8 a;
        a[0] = (__bf16)p0[0]; a[1] = (__bf16)p0[1];
        a[2] = (__bf16)p0[2]; a[3] = (__bf16)p0[3];
        a[4] = (__bf16)p1[0]; a[5] = (__bf16)p1[1];
        a[6] = (__bf16)p1[2]; a[7] = (__bf16)p1[3];
        #pragma unroll
        for (int ni = 0; ni < 4; ni++)
          acc[mi][ni] = __builtin_amdgcn_mfma_f32_16x16x32_bf16(
              a, bfr[ni], acc[mi][ni], 0, 0, 0);
      }
    }
    if (more) store_b(Bsm[nxt], bo, bc, bv);
    __syncthreads();
  }

  if (bias_tile) {  // virtual chunk: x == 1, weights = pb (already staged)
    const int cur = nreal & 1;
    #pragma unroll
    for (int kk = 0; kk < 2; kk++) {
      bf16x8 bfr[4];
      #pragma unroll
      for (int ni = 0; ni < 4; ni++) {
        int row = wn * 64 + ni * 16 + rl;
        int byte = row * 128 + ((kk * 64 + q * 16) ^ ((row & 7) << 4));
        bfr[ni] = *(const bf16x8*)((const char*)Bsm[cur] + byte);
      }
      #pragma unroll
      for (int mi = 0; mi < 4; mi++) {
        f32x4 p0 = lf[mi][kk][0], p1 = lf[mi][kk][1];
        bf16x8 a;
        a[0] = (__bf16)p0[0]; a[1] = (__bf16)p0[1];
        a[2] = (__bf16)p0[2]; a[3] = (__bf16)p0[3];
        a[4] = (__bf16)p1[0]; a[5] = (__bf16)p1[1];
        a[6] = (__bf16)p1[2]; a[7] = (__bf16)p1[3];
        #pragma unroll
        for (int ni = 0; ni < 4; ni++)
          acc[mi][ni] = __builtin_amdgcn_mfma_f32_16x16x32_bf16(
              a, bfr[ni], acc[mi][ni], 0, 0, 0);
      }
    }
  }

  // epilogue: partial[s][m0+row][n0+col]
  float* dst = partial + ((size_t)s * BATCH + m0) * OUTF + n0;
  #pragma unroll
  for (int mi = 0; mi < 4; mi++)
    #pragma unroll
    for (int ni = 0; ni < 4; ni++)
      #pragma unroll
      for (int r = 0; r < 4; r++) {
        int row = wm * 64 + mi * 16 + q * 4 + r;  // D row = (lane>>4)*4 + reg
        int col = wn * 64 + ni * 16 + rl;         // D col = lane&15
        dst[(size_t)row * OUTF + col] = acc[mi][ni][r];
      }
}

// ---------------- kernel 3: split-K reduce ----------------
__global__ __launch_bounds__(256) void reduce_kernel(
    const float* __restrict__ partial, float* __restrict__ out) {
  size_t e = ((size_t)blockIdx.x * 256 + threadIdx.x) * 4;
  f32x4 sum = (f32x4){0.f, 0.f, 0.f, 0.f};
  #pragma unroll
  for (int s = 0; s < SPLITK; s++)
    sum += *(const f32x4*)(partial + (size_t)s * BATCH * OUTF + e);
  *(f32x4*)(out + e) = sum;
}

extern "C" void kernel_launch(void* const* d_in, const int* in_sizes, int n_in,
                              void* d_out, int out_size, void* d_ws, size_t ws_size,
                              hipStream_t stream) {
  const float* x  = (const float*)d_in[0];
  const float* gw = (const float*)d_in[1];
  const float* gb = (const float*)d_in[2];
  const float* pw = (const float*)d_in[3];
  const float* pb = (const float*)d_in[4];
  float* out = (float*)d_out;

  float* leaf    = (float*)d_ws;                       // 256 KB
  float* partial = (float*)((char*)d_ws + (1 << 19));  // 16 x 2 MB = 33.5 MB

  leaf_kernel<<<BATCH / 4, 256, 0, stream>>>(x, gw, gb, leaf);
  gemm_kernel<<<(BATCH / BM) * (OUTF / BN) * SPLITK, THREADS, 0, stream>>>(
      x, pw, pb, leaf, partial);
  reduce_kernel<<<(BATCH * OUTF) / (256 * 4), 256, 0, stream>>>(partial, out);
}

// Round 4
// 72.339 us; speedup vs baseline: 2.7712x; 1.0038x over previous
//
#include <hip/hip_runtime.h>
#include <hip/hip_bf16.h>

#define TDEPTH 6
#define NLEAF 64
#define NGATE 63
#define INF 512
#define OUTF 512
#define BATCH 1024

#define BM 256
#define BN 128
#define SPLITK 16
#define KCH 513     // 512 real i-chunks + 1 virtual bias chunk (x==1, W=pb)
#define THREADS 512
#define XPITCH 36   // f32 pitch for x slice rows (144 B, 16B-aligned, bank-walk +4)
#define BPITCH 144  // byte pitch for B LDS rows (128 B data + 16 B pad)

typedef __attribute__((ext_vector_type(4))) float f32x4;
typedef __attribute__((ext_vector_type(8))) __bf16 bf16x8;

// ---------------- kernel 1: leaf probabilities ----------------
__global__ __launch_bounds__(256) void leaf_kernel(
    const float* __restrict__ x, const float* __restrict__ gw,
    const float* __restrict__ gb, float* __restrict__ leaf) {
  const int wid = threadIdx.x >> 6, lane = threadIdx.x & 63;
  const int b = blockIdx.x * 4 + wid;
  __shared__ float g[4][NLEAF];
  if (lane < NGATE) {
    const float* xr = x + (size_t)b * INF;
    float a0 = 0.f, a1 = 0.f, a2 = 0.f, a3 = 0.f;
    #pragma unroll 4
    for (int i = 0; i < INF; i += 4) {
      a0 += xr[i + 0] * gw[(i + 0) * NGATE + lane];
      a1 += xr[i + 1] * gw[(i + 1) * NGATE + lane];
      a2 += xr[i + 2] * gw[(i + 2) * NGATE + lane];
      a3 += xr[i + 3] * gw[(i + 3) * NGATE + lane];
    }
    float t = (a0 + a1) + (a2 + a3) + gb[lane];
    g[wid][lane] = 1.0f / (1.0f + __expf(-t));
  }
  __syncthreads();
  float p = 1.0f;
  #pragma unroll
  for (int d = 0; d < TDEPTH; d++) {
    int prefix = lane >> (TDEPTH - 1 - d);
    int node = (1 << d) - 1 + (prefix >> 1);
    float gv = g[wid][node];
    p *= (prefix & 1) ? (1.0f - gv) : gv;
  }
  leaf[(size_t)b * NLEAF + lane] = p;
}

// raw barrier: NO vmcnt drain (prefetch loads stay in flight across it)
__device__ __forceinline__ void sync_raw() {
  asm volatile("s_waitcnt lgkmcnt(0)" ::: "memory");
  __builtin_amdgcn_sched_barrier(0);
  __builtin_amdgcn_s_barrier();
  __builtin_amdgcn_sched_barrier(0);
}

// ---------------- kernel 2: hybrid fused GEMM ----------------
// A-frags in registers (lf resident, x from LDS); B: global->reg (depth-2
// prefetch) -> cvt -> padded LDS (144B pitch), one raw barrier per K-step.
__global__ __launch_bounds__(THREADS, 2) void gemm_kernel(
    const float* __restrict__ x, const float* __restrict__ pw,
    const float* __restrict__ pb, const float* __restrict__ leaf,
    float* __restrict__ partial) {
  __shared__ __align__(16) float xsm[BM * XPITCH];      // 36.9 KB
  __shared__ __align__(16) __bf16 Bsm[2][BN * (BPITCH / 2)];  // 2 x 18 KB

  const int tid = threadIdx.x;
  const int lane = tid & 63;
  const int wid = tid >> 6;
  const int wm = wid >> 1, wn = wid & 1;   // 4x2 wave grid, 64x64 per wave
  const int q = lane >> 4, rl = lane & 15;

  // XCD-chunked swizzle: the 4 mb-blocks of one (nb,s) group share an XCD L2
  const int bid = blockIdx.x;
  const int L = (bid & 7) * 32 + (bid >> 3);
  const int mb = L & 3, g = L >> 2;
  const int nb = g >> 4, s = g & 15;
  const int m0 = mb * BM, n0 = nb * BN;
  const int cs = (s * KCH) / SPLITK;
  const int ce = ((s + 1) * KCH) / SPLITK;
  const int nreal = min(ce, INF) - cs;     // 32 for all s
  const int total = nreal + ((ce == KCH) ? 1 : 0);  // +1 bias step on s==15

  // leaf fragments -> registers, resident across the whole K-loop
  f32x4 lf[4][2][2];
  #pragma unroll
  for (int mi = 0; mi < 4; mi++) {
    const float* lr = leaf + (size_t)(m0 + wm * 64 + mi * 16 + rl) * NLEAF + q * 8;
    #pragma unroll
    for (int kk = 0; kk < 2; kk++) {
      lf[mi][kk][0] = *(const f32x4*)(lr + kk * 32);
      lf[mi][kk][1] = *(const f32x4*)(lr + kk * 32 + 4);
    }
  }

  // B staging assignment: thread -> (row bo, 64B-contiguous quarter bc)
  const int bo = tid >> 2, bc = tid & 3;
  const float* pwrow = pw + (size_t)(n0 + bo) * (INF * NLEAF) + bc * 16;
  const float* pbrow = pb + (size_t)(n0 + bo) * NLEAF + bc * 16;

  f32x4 acc[4][4];
  #pragma unroll
  for (int mi = 0; mi < 4; mi++)
    #pragma unroll
    for (int ni = 0; ni < 4; ni++) acc[mi][ni] = (f32x4){0.f, 0.f, 0.f, 0.f};

  f32x4 bvA[4], bvB[4];

  // ---- prologue: load steps 0,1; stage x slice; write step 0 to LDS ----
  {
    const float* s0 = pwrow + (size_t)cs * NLEAF;
    #pragma unroll
    for (int j = 0; j < 4; j++) bvA[j] = *(const f32x4*)(s0 + j * 4);
    const float* s1 = pwrow + (size_t)(cs + 1) * NLEAF;
    #pragma unroll
    for (int j = 0; j < 4; j++) bvB[j] = *(const f32x4*)(s1 + j * 4);
  }
  {
    int r = tid >> 1, h = tid & 1;
    const float* src = x + (size_t)(m0 + r) * INF + cs + h * 16;
    float* dst = xsm + r * XPITCH + h * 16;
    #pragma unroll
    for (int j = 0; j < 4; j++)
      *(f32x4*)(dst + j * 4) = *(const f32x4*)(src + j * 4);
  }
  {
    #pragma unroll
    for (int h = 0; h < 2; h++) {
      f32x4 lo = bvA[2 * h], hi = bvA[2 * h + 1];
      bf16x8 w;
      w[0] = (__bf16)lo[0]; w[1] = (__bf16)lo[1];
      w[2] = (__bf16)lo[2]; w[3] = (__bf16)lo[3];
      w[4] = (__bf16)hi[0]; w[5] = (__bf16)hi[1];
      w[6] = (__bf16)hi[2]; w[7] = (__bf16)hi[3];
      *(bf16x8*)((char*)&Bsm[0][0] + bo * BPITCH + bc * 32 + h * 16) = w;
    }
  }
  sync_raw();

  // ---- main loop: one raw barrier per step ----
  auto step_body = [&](int t, f32x4(&Rld)[4], f32x4(&Rst)[4],
                       __bf16* cur, __bf16* nxt) {
    // (1) issue prefetch for step t+2 (stays in flight across the barrier)
    if (t + 2 < total) {
      const float* s2 = (t + 2 < nreal)
          ? pwrow + (size_t)(cs + t + 2) * NLEAF : pbrow;
      #pragma unroll
      for (int j = 0; j < 4; j++) Rld[j] = *(const f32x4*)(s2 + j * 4);
    }
    // (2) compute step t from `cur`
    float xv[4];
    #pragma unroll
    for (int mi = 0; mi < 4; mi++) {
      float v = xsm[(wm * 64 + mi * 16 + rl) * XPITCH + (t & 31)];
      xv[mi] = (t < nreal) ? v : 1.0f;   // bias step: x == 1
    }
    #pragma unroll
    for (int kk = 0; kk < 2; kk++) {
      bf16x8 bfr[4];
      #pragma unroll
      for (int ni = 0; ni < 4; ni++) {
        int row = wn * 64 + ni * 16 + rl;
        bfr[ni] = *(const bf16x8*)((const char*)cur + row * BPITCH +
                                   kk * 64 + q * 16);
      }
      #pragma unroll
      for (int mi = 0; mi < 4; mi++) {
        f32x4 p0 = lf[mi][kk][0] * xv[mi];
        f32x4 p1 = lf[mi][kk][1] * xv[mi];
        bf16x8 a;
        a[0] = (__bf16)p0[0]; a[1] = (__bf16)p0[1];
        a[2] = (__bf16)p0[2]; a[3] = (__bf16)p0[3];
        a[4] = (__bf16)p1[0]; a[5] = (__bf16)p1[1];
        a[6] = (__bf16)p1[2]; a[7] = (__bf16)p1[3];
        #pragma unroll
        for (int ni = 0; ni < 4; ni++)
          acc[mi][ni] = __builtin_amdgcn_mfma_f32_16x16x32_bf16(
              a, bfr[ni], acc[mi][ni], 0, 0, 0);
      }
    }
    // (3) cvt + write step t+1 to `nxt` (waits only its own loads: vmcnt(4))
    if (t + 1 < total) {
      #pragma unroll
      for (int h = 0; h < 2; h++) {
        f32x4 lo = Rst[2 * h], hi = Rst[2 * h + 1];
        bf16x8 w;
        w[0] = (__bf16)lo[0]; w[1] = (__bf16)lo[1];
        w[2] = (__bf16)lo[2]; w[3] = (__bf16)lo[3];
        w[4] = (__bf16)hi[0]; w[5] = (__bf16)hi[1];
        w[6] = (__bf16)hi[2]; w[7] = (__bf16)hi[3];
        *(bf16x8*)((char*)nxt + bo * BPITCH + bc * 32 + h * 16) = w;
      }
    }
    sync_raw();
  };

  __bf16* B0 = &Bsm[0][0];
  __bf16* B1 = &Bsm[1][0];
  for (int t = 0; t < total; t += 2) {
    step_body(t, bvA, bvB, B0, B1);
    if (t + 1 < total) step_body(t + 1, bvB, bvA, B1, B0);
  }

  // ---- epilogue: partial[s][m0+row][n0+col] ----
  float* dst = partial + ((size_t)s * BATCH + m0) * OUTF + n0;
  #pragma unroll
  for (int mi = 0; mi < 4; mi++)
    #pragma unroll
    for (int ni = 0; ni < 4; ni++)
      #pragma unroll
      for (int r = 0; r < 4; r++) {
        int row = wm * 64 + mi * 16 + q * 4 + r;  // D row = (lane>>4)*4 + reg
        int col = wn * 64 + ni * 16 + rl;         // D col = lane&15
        dst[(size_t)row * OUTF + col] = acc[mi][ni][r];
      }
}

// ---------------- kernel 3: split-K reduce ----------------
__global__ __launch_bounds__(256) void reduce_kernel(
    const float* __restrict__ partial, float* __restrict__ out) {
  size_t e = ((size_t)blockIdx.x * 256 + threadIdx.x) * 4;
  f32x4 sum = (f32x4){0.f, 0.f, 0.f, 0.f};
  #pragma unroll
  for (int s = 0; s < SPLITK; s++)
    sum += *(const f32x4*)(partial + (size_t)s * BATCH * OUTF + e);
  *(f32x4*)(out + e) = sum;
}

extern "C" void kernel_launch(void* const* d_in, const int* in_sizes, int n_in,
                              void* d_out, int out_size, void* d_ws, size_t ws_size,
                              hipStream_t stream) {
  const float* x  = (const float*)d_in[0];
  const float* gw = (const float*)d_in[1];
  const float* gb = (const float*)d_in[2];
  const float* pw = (const float*)d_in[3];
  const float* pb = (const float*)d_in[4];
  float* out = (float*)d_out;

  float* leaf    = (float*)d_ws;                       // 256 KB
  float* partial = (float*)((char*)d_ws + (1 << 19));  // 16 x 2 MB

  leaf_kernel<<<BATCH / 4, 256, 0, stream>>>(x, gw, gb, leaf);
  gemm_kernel<<<(BATCH / BM) * (OUTF / BN) * SPLITK, THREADS, 0, stream>>>(
      x, pw, pb, leaf, partial);
  reduce_kernel<<<(BATCH * OUTF) / (256 * 4), 256, 0, stream>>>(partial, out);
}